// Round 11
// baseline (727.880 us; speedup 1.0000x reference)
//
#include <hip/hip_runtime.h>
#include <math.h>

typedef short s16x8 __attribute__((ext_vector_type(8)));
typedef float f32x4 __attribute__((ext_vector_type(4)));
typedef unsigned short u16;

// ---------------- problem constants ----------------
#define B_    32
#define CIN   128
#define CHID  256
#define H_    60
#define W_    80
#define COUT  65
#define HP    480
#define WP    640
#define TOPK  1000
#define CAND_MAX 8192
#define DET_THRESH 0.015f

// ---------------- output layout (floats) ----------------
#define LOGITS_N (B_*COUT*H_*W_)
#define PROB_N   (B_*HP*WP)
#define PROB_OFF (LOGITS_N)
#define NMS_OFF  (PROB_OFF + PROB_N)
#define PRED_OFF (NMS_OFF + PROB_N)

// ---------------- workspace layout (float offsets) ----------------
// WB: conv3 weights, 3 bf16 planes (hi,mid,lo), LINEAR:
//   [ocq4][icc4][tap9][plane3][ocl64][icl32]
#define WB_FN    442368
#define SA_OFF   WB_FN
#define TA_OFF   (SA_OFF + 256)
#define TB_OFF   (TA_OFF + 256)
#define WT1_N    (COUT*CHID)
#define WT1_OFF  (TB_OFF + 128)
#define H_OFF    (WT1_OFF + WT1_N)
#define H_N      (B_*H_*W_*CHID)
#define CAND_OFF (H_OFF + H_N)
#define CNT_OFF  (CAND_OFF + B_*CAND_MAX)
#define CNT_N    (32*32)
#define KTH_OFF  (CNT_OFF + CNT_N)
#define WT_N     (CHID*CIN*9)

// bf16 helpers (RNE)
__device__ __forceinline__ u16 f2bf(float x) {
    unsigned u = __float_as_uint(x);
    return (u16)((u + 0x7fffu + ((u >> 16) & 1u)) >> 16);
}
__device__ __forceinline__ float bf2f(u16 h) {
    return __uint_as_float(((unsigned)h) << 16);
}

// async global->LDS, 16B per lane (lds dest = uniform base + lane*16)
__device__ __forceinline__ void gload_lds16(const float* g, float* l) {
    __builtin_amdgcn_global_load_lds(
        (const __attribute__((address_space(1))) void*)g,
        (__attribute__((address_space(3))) void*)l, 16, 0, 0);
}

#define MFMA16 __builtin_amdgcn_mfma_f32_16x16x32_bf16

// =====================================================================
// K0: prep — WB (conv3 weights 3-plane exact bf16 split, linear),
// sa/ta conv3 BN, tb + wt1 (conv1 folded).
// =====================================================================
__global__ void prep_kernel(const float* __restrict__ wa,
                            const float* __restrict__ ba, const float* __restrict__ ga,
                            const float* __restrict__ bta, const float* __restrict__ ma,
                            const float* __restrict__ va,
                            const float* __restrict__ wb, const float* __restrict__ bb,
                            const float* __restrict__ gb, const float* __restrict__ btb,
                            const float* __restrict__ mb, const float* __restrict__ vb,
                            u16* __restrict__ WBo,
                            float* __restrict__ sa, float* __restrict__ ta,
                            float* __restrict__ tb, float* __restrict__ wt1)
{
    int gid = blockIdx.x * 256 + threadIdx.x;
    if (gid < WT_N) {
        int icl = gid & 31;
        int ocl = (gid >> 5) & 63;
        int rest = gid >> 11;          // [0,144)
        int tap = rest % 9;
        int cq = rest / 9;             // [0,16)
        int icc = cq & 3, ocq = cq >> 2;
        float v = wa[(((ocq * 64 + ocl) * CIN) + icc * 32 + icl) * 9 + tap];
        u16 hh = f2bf(v); float r1 = v - bf2f(hh);
        u16 mm2 = f2bf(r1); float r2 = r1 - bf2f(mm2);
        u16 ll = f2bf(r2);
        size_t base = ((size_t)(((ocq * 4 + icc) * 9 + tap) * 3)) * 2048
                      + ocl * 32 + icl;
        WBo[base] = hh;
        WBo[base + 2048] = mm2;
        WBo[base + 4096] = ll;
    } else if (gid < WT_N + 256) {
        int oc = gid - WT_N;
        float inv = ga[oc] / sqrtf(va[oc] + 1e-5f);
        sa[oc] = inv;
        ta[oc] = (ba[oc] - ma[oc]) * inv + bta[oc];
    } else if (gid < WT_N + 256 + COUT) {
        int oc = gid - (WT_N + 256);
        float inv = gb[oc] / sqrtf(vb[oc] + 1e-5f);
        tb[oc] = (bb[oc] - mb[oc]) * inv + btb[oc];
    } else if (gid < WT_N + 256 + COUT + WT1_N) {
        int i = gid - (WT_N + 256 + COUT);
        int oc = i >> 8;
        float inv = gb[oc] / sqrtf(vb[oc] + 1e-5f);
        wt1[i] = wb[i] * inv;
    }
}

// =====================================================================
// K1: conv3x3 via 6-term split-bf16 MFMA (hh+hm+mh+hl+mm+lh).
// Round-11 change: A-frag REGISTER REUSE across dy — tap loop becomes
// 3 dx-groups; 6 rows x 3 planes hoisted into regs once per group and
// shared by the 3 dy taps (12 (pb,dy) pairs). LDS b128 reads per wave
// per icc: 108 -> 54, attacking the measured LDS-pipe bound (LDS demand
// 2x MFMA demand at round 10 -> MfmaUtil 52%).
// =====================================================================
__global__ __launch_bounds__(256, 2) void conv3_kernel(const float* __restrict__ x,
                                                       const u16* __restrict__ WB,
                                                       const float* __restrict__ sa,
                                                       const float* __restrict__ ta,
                                                       float* __restrict__ h)
{
    __shared__ __align__(16) u16 xsA[3 * 4536];   // 27216 B: hi, mid, lo planes

    // bijective XCD swizzle: 2400 blocks = 8 * 300
    int d = blockIdx.x;
    int o = (d & 7) * 300 + (d >> 3);
    int tile = o % 75;
    int b = o / 75;
    int ty = tile / 5, tx = tile % 5;
    int y0 = ty * 4, x0 = tx * 16;

    int t = threadIdx.x;
    int wv = __builtin_amdgcn_readfirstlane(t >> 6);   // 0..3 = ocq
    int lane = t & 63;
    int cx = lane & 15;
    int kg = lane >> 4;
    int icl0 = kg * 8;

    const float* xb = x + (size_t)b * CIN * H_ * W_;

    f32x4 acc[4][4];               // [pb(y-row)][f(oc-subtile)] = 64 acc regs
#pragma unroll
    for (int pb = 0; pb < 4; ++pb)
#pragma unroll
        for (int f = 0; f < 4; ++f) acc[pb][f] = (f32x4)(0.f);

#pragma unroll 1
    for (int icc = 0; icc < 4; ++icc) {
        __syncthreads();
        // stage A slab: 6y x 18x x 32ic, f32 -> (hi,mid,lo) bf16
        // row stride 42 u16 (21 dwords, odd): staging writes conflict-free
        const float* xc = xb + icc * 32 * (H_ * W_);
#pragma unroll
        for (int j = 0; j < 14; ++j) {
            int e = t + j * 256;
            if (e < 3456) {
                int xx = e % 18;
                int yy = (e / 18) % 6;
                int icl = e / 108;
                int gy = y0 + yy - 1, gx = x0 + xx - 1;
                float v = 0.f;
                if (gy >= 0 && gy < H_ && gx >= 0 && gx < W_)
                    v = xc[icl * (H_ * W_) + gy * W_ + gx];
                u16 hh = f2bf(v); float r1 = v - bf2f(hh);
                u16 mm2 = f2bf(r1); float r2 = r1 - bf2f(mm2);
                u16 ll = f2bf(r2);
                int pos = yy * 18 + xx;
                int wu = pos * 42 + (icl ^ (pos & 8));
                xsA[wu] = hh;
                xsA[4536 + wu] = mm2;
                xsA[9072 + wu] = ll;
            }
        }
        __syncthreads();

        // 3 dx-groups: hoist A rows 0..5 (3 planes) into regs, reuse for
        // the 3 dy taps of this column window.
#pragma unroll 1
        for (int dx = 0; dx < 3; ++dx) {
            s16x8 Ah[6], Am[6], Al[6];
#pragma unroll
            for (int row = 0; row < 6; ++row) {
                int pos = row * 18 + cx + dx;
                int au = pos * 42 + (icl0 ^ (pos & 8));
                Ah[row] = *(const s16x8*)&xsA[au];
                Am[row] = *(const s16x8*)&xsA[4536 + au];
                Al[row] = *(const s16x8*)&xsA[9072 + au];
            }
#pragma unroll
            for (int dy = 0; dy < 3; ++dy) {
                int tap = dy * 3 + dx;
                const u16* bb_ = WB + ((size_t)(((wv * 4 + icc) * 9 + tap) * 3)) * 2048;
                s16x8 Bh[4], Bm[4], Bl[4];
#pragma unroll
                for (int f = 0; f < 4; ++f) {
                    int bu = (f * 16 + cx) * 32 + icl0;
                    Bh[f] = *(const s16x8*)&bb_[bu];
                    Bm[f] = *(const s16x8*)&bb_[2048 + bu];
                    Bl[f] = *(const s16x8*)&bb_[4096 + bu];
                }
#pragma unroll
                for (int pb = 0; pb < 4; ++pb) {
                    int row = pb + dy;
#pragma unroll
                    for (int f = 0; f < 4; ++f) {
                        acc[pb][f] = MFMA16(Ah[row], Bh[f], acc[pb][f], 0, 0, 0);
                        acc[pb][f] = MFMA16(Ah[row], Bm[f], acc[pb][f], 0, 0, 0);
                        acc[pb][f] = MFMA16(Am[row], Bh[f], acc[pb][f], 0, 0, 0);
                        acc[pb][f] = MFMA16(Ah[row], Bl[f], acc[pb][f], 0, 0, 0);
                        acc[pb][f] = MFMA16(Am[row], Bm[f], acc[pb][f], 0, 0, 0);
                        acc[pb][f] = MFMA16(Al[row], Bh[f], acc[pb][f], 0, 0, 0);
                    }
                }
            }
        }
    }

    // epilogue: C lane map n=lane&15 (oc), m=(lane>>4)*4+r (x-col); BN + ReLU
#pragma unroll
    for (int f = 0; f < 4; ++f) {
        int oc = wv * 64 + f * 16 + cx;
        float s_ = sa[oc], t_ = ta[oc];
#pragma unroll
        for (int pb = 0; pb < 4; ++pb) {
            int y = y0 + pb;
#pragma unroll
            for (int r = 0; r < 4; ++r) {
                int xc2 = x0 + kg * 4 + r;
                size_t addr = ((size_t)(b * (H_ * W_) + y * W_ + xc2)) * CHID + oc;
                h[addr] = fmaxf(fmaf(acc[pb][f][r], s_, t_), 0.f);
            }
        }
    }
}

// =====================================================================
// K2: conv1x1 (256->65) + BN: weights staged in 64KB LDS via gload_lds
// =====================================================================
__global__ __launch_bounds__(256) void conv1_kernel(const float* __restrict__ h,
                                                    const float* __restrict__ wt1,
                                                    const float* __restrict__ tb,
                                                    float* __restrict__ logits,
                                                    float* __restrict__ prob)
{
    __shared__ __align__(16) float ws_[64 * 256];
    int t = threadIdx.x;
    int wave = t >> 6, lane = t & 63;

    for (int k = wave; k < 64; k += 4)
        gload_lds16(wt1 + k * 256 + lane * 4, &ws_[k * 256]);

    int p = blockIdx.x * 256 + t;
    const float* hp = h + (size_t)p * CHID;
    const float* w64g = wt1 + 64 * 256;

    float acc[COUT];
#pragma unroll
    for (int oc = 0; oc < COUT; ++oc) acc[oc] = 0.f;

    __syncthreads();

#pragma unroll 2
    for (int kc = 0; kc < 32; ++kc) {
        float4 h0 = *(const float4*)(hp + kc * 8);
        float4 h1 = *(const float4*)(hp + kc * 8 + 4);
        float hv[8] = {h0.x, h0.y, h0.z, h0.w, h1.x, h1.y, h1.z, h1.w};
        {
            float4 w0 = *(const float4*)(w64g + kc * 8);
            float4 w1 = *(const float4*)(w64g + kc * 8 + 4);
            float a = acc[64];
            a = fmaf(w0.x, hv[0], a); a = fmaf(w0.y, hv[1], a);
            a = fmaf(w0.z, hv[2], a); a = fmaf(w0.w, hv[3], a);
            a = fmaf(w1.x, hv[4], a); a = fmaf(w1.y, hv[5], a);
            a = fmaf(w1.z, hv[6], a); a = fmaf(w1.w, hv[7], a);
            acc[64] = a;
        }
#pragma unroll
        for (int oc = 0; oc < 64; ++oc) {
            const float* wr = ws_ + oc * 256 + kc * 8;
            float4 w0 = *(const float4*)wr;
            float4 w1 = *(const float4*)(wr + 4);
            float a = acc[oc];
            a = fmaf(w0.x, hv[0], a); a = fmaf(w0.y, hv[1], a);
            a = fmaf(w0.z, hv[2], a); a = fmaf(w0.w, hv[3], a);
            a = fmaf(w1.x, hv[4], a); a = fmaf(w1.y, hv[5], a);
            a = fmaf(w1.z, hv[6], a); a = fmaf(w1.w, hv[7], a);
            acc[oc] = a;
        }
    }

    int b = p / (H_ * W_);
    int yx = p % (H_ * W_);
    int y = yx / W_;
    int xx = yx % W_;

    float v[COUT];
#pragma unroll
    for (int oc = 0; oc < COUT; ++oc)
        v[oc] = acc[oc] + tb[oc];

#pragma unroll
    for (int oc = 0; oc < COUT; ++oc)
        logits[((size_t)(b * COUT + oc)) * (H_ * W_) + yx] = v[oc];

    float* pb = prob + (size_t)b * (HP * WP);
#pragma unroll
    for (int r1 = 0; r1 < 8; ++r1) {
        float4 a0, a1;
        a0.x = v[r1 * 8 + 0]; a0.y = v[r1 * 8 + 1]; a0.z = v[r1 * 8 + 2]; a0.w = v[r1 * 8 + 3];
        a1.x = v[r1 * 8 + 4]; a1.y = v[r1 * 8 + 5]; a1.z = v[r1 * 8 + 6]; a1.w = v[r1 * 8 + 7];
        float* dst = pb + (y * 8 + r1) * WP + xx * 8;
        *(float4*)dst = a0;
        *(float4*)(dst + 4) = a1;
    }
}

// =====================================================================
// K3: 9x9 local-max keep + candidate compaction (1 global atomic/block)
// =====================================================================
__global__ __launch_bounds__(256) void nms_kernel(const float* __restrict__ prob,
                                                  float* __restrict__ keep_out,
                                                  float* __restrict__ cand,
                                                  int* __restrict__ cnt)
{
    __shared__ float xs[40][40];
    __shared__ float rmax[40][32];
    __shared__ float clist[1024];
    __shared__ int csh;
    __shared__ int gbase;

    int bid = blockIdx.x;
    int tx = bid % 20;
    int ty = (bid / 20) % 15;
    int b = bid / 300;
    const float* pb = prob + (size_t)b * (HP * WP);
    int t = threadIdx.x;

    if (t == 0) csh = 0;

    for (int idx = t; idx < 1600; idx += 256) {
        int c = idx % 40, r = idx / 40;
        int gy = ty * 32 - 4 + r;
        int gx = tx * 32 - 4 + c;
        float v = -INFINITY;
        if (gy >= 0 && gy < HP && gx >= 0 && gx < WP) v = pb[gy * WP + gx];
        xs[r][c] = v;
    }
    __syncthreads();

    for (int idx = t; idx < 1280; idx += 256) {
        int c = idx & 31, r = idx >> 5;
        float m = xs[r][c];
#pragma unroll
        for (int d = 1; d < 9; ++d) m = fmaxf(m, xs[r][c + d]);
        rmax[r][c] = m;
    }
    __syncthreads();

    for (int idx = t; idx < 1024; idx += 256) {
        int c = idx & 31, ro = idx >> 5;
        float m = rmax[ro][c];
#pragma unroll
        for (int d = 1; d < 9; ++d) m = fmaxf(m, rmax[ro + d][c]);
        float v = xs[ro + 4][c + 4];
        float keep = (v == m) ? v : 0.f;
        keep_out[(size_t)b * (HP * WP) + (ty * 32 + ro) * WP + tx * 32 + c] = keep;
        if (keep > 0.f) {
            int i = atomicAdd(&csh, 1);
            clist[i] = keep;
        }
    }
    __syncthreads();

    int m = csh;
    if (m > 0) {
        if (t == 0) gbase = atomicAdd(&cnt[b * 32], m);
        __syncthreads();
        int gb = gbase;
        for (int i = t; i < m; i += 256) {
            int dst = gb + i;
            if (dst < CAND_MAX) cand[b * CAND_MAX + dst] = clist[i];
        }
    }
}

// =====================================================================
// K4: exact kth-largest (k=1000) per batch via 4-pass radix select
// =====================================================================
__global__ __launch_bounds__(256) void select_kernel(const float* __restrict__ cand,
                                                     const int* __restrict__ cnt,
                                                     float* __restrict__ kth)
{
    __shared__ unsigned hist[256];
    __shared__ unsigned sh_prefix, sh_K;

    int b = blockIdx.x;
    int t = threadIdx.x;
    int n = cnt[b * 32];
    if (n > CAND_MAX) n = CAND_MAX;
    if (n < TOPK) {
        if (t == 0) kth[b] = 0.f;
        return;
    }
    if (t == 0) { sh_prefix = 0u; sh_K = TOPK; }
    __syncthreads();
    const float* cb = cand + b * CAND_MAX;

    for (int pass = 3; pass >= 0; --pass) {
        hist[t] = 0u;
        __syncthreads();
        unsigned prefix = sh_prefix;
        unsigned himask = (pass == 3) ? 0u : (0xFFFFFFFFu << ((pass + 1) * 8));
        for (int i = t; i < n; i += 256) {
            unsigned u = __float_as_uint(cb[i]);
            if ((u & himask) == prefix)
                atomicAdd(&hist[(u >> (pass * 8)) & 255], 1u);
        }
        __syncthreads();
        if (t == 0) {
            unsigned K = sh_K, cum = 0;
            int sel = 0;
            for (int v2 = 255; v2 >= 0; --v2) {
                if (cum + hist[v2] >= K) { sel = v2; sh_K = K - cum; break; }
                cum += hist[v2];
            }
            sh_prefix = prefix | ((unsigned)sel << (pass * 8));
        }
        __syncthreads();
    }
    if (t == 0) kth[b] = __uint_as_float(sh_prefix);
}

// =====================================================================
// K5: threshold with kth + binarize
// =====================================================================
__global__ __launch_bounds__(256) void thresh_kernel(const float* __restrict__ keep,
                                                     const float* __restrict__ kth,
                                                     float* __restrict__ prob_nms,
                                                     float* __restrict__ pred)
{
    int i4 = blockIdx.x * 256 + threadIdx.x;
    int b = i4 / (HP * WP / 4);
    float tv = kth[b];
    float4 v = ((const float4*)keep)[i4];
    float4 o;
    o.x = (v.x >= tv) ? v.x : 0.f;
    o.y = (v.y >= tv) ? v.y : 0.f;
    o.z = (v.z >= tv) ? v.z : 0.f;
    o.w = (v.w >= tv) ? v.w : 0.f;
    ((float4*)prob_nms)[i4] = o;
    float4 pr;
    pr.x = (o.x >= DET_THRESH) ? 1.f : 0.f;
    pr.y = (o.y >= DET_THRESH) ? 1.f : 0.f;
    pr.z = (o.z >= DET_THRESH) ? 1.f : 0.f;
    pr.w = (o.w >= DET_THRESH) ? 1.f : 0.f;
    ((float4*)pred)[i4] = pr;
}

// =====================================================================
extern "C" void kernel_launch(void* const* d_in, const int* in_sizes, int n_in,
                              void* d_out, int out_size, void* d_ws, size_t ws_size,
                              hipStream_t stream) {
    const float* x   = (const float*)d_in[0];
    const float* wa  = (const float*)d_in[1];
    const float* ba  = (const float*)d_in[2];
    const float* ga  = (const float*)d_in[3];
    const float* bta = (const float*)d_in[4];
    const float* ma  = (const float*)d_in[5];
    const float* va  = (const float*)d_in[6];
    const float* wb  = (const float*)d_in[7];
    const float* bb  = (const float*)d_in[8];
    const float* gb  = (const float*)d_in[9];
    const float* btb = (const float*)d_in[10];
    const float* mb  = (const float*)d_in[11];
    const float* vb  = (const float*)d_in[12];

    float* out = (float*)d_out;
    float* ws  = (float*)d_ws;

    u16*   WB   = (u16*)ws;
    float* sa   = ws + SA_OFF;
    float* ta   = ws + TA_OFF;
    float* tbv  = ws + TB_OFF;
    float* wt1  = ws + WT1_OFF;
    float* h    = ws + H_OFF;
    float* cand = ws + CAND_OFF;
    int*   cnt  = (int*)(ws + CNT_OFF);
    float* kth  = ws + KTH_OFF;

    hipMemsetAsync((void*)cnt, 0, CNT_N * sizeof(int), stream);

    {
        int total = WT_N + 256 + COUT + WT1_N;
        prep_kernel<<<(total + 255) / 256, 256, 0, stream>>>(
            wa, ba, ga, bta, ma, va, wb, bb, gb, btb, mb, vb, WB, sa, ta, tbv, wt1);
    }

    conv3_kernel<<<2400, 256, 0, stream>>>(x, WB, sa, ta, h);

    conv1_kernel<<<(B_ * H_ * W_) / 256, 256, 0, stream>>>(
        h, wt1, tbv, out, out + PROB_OFF);

    nms_kernel<<<32 * 15 * 20, 256, 0, stream>>>(
        out + PROB_OFF, out + NMS_OFF, cand, cnt);

    select_kernel<<<B_, 256, 0, stream>>>(cand, cnt, kth);

    thresh_kernel<<<(PROB_N / 4) / 256, 256, 0, stream>>>(
        out + NMS_OFF, kth, out + NMS_OFF, out + PRED_OFF);
}

// Round 12
// 709.073 us; speedup vs baseline: 1.0265x; 1.0265x over previous
//
#include <hip/hip_runtime.h>
#include <math.h>

typedef short s16x8 __attribute__((ext_vector_type(8)));
typedef float f32x4 __attribute__((ext_vector_type(4)));
typedef unsigned short u16;

// ---------------- problem constants ----------------
#define B_    32
#define CIN   128
#define CHID  256
#define H_    60
#define W_    80
#define COUT  65
#define HP    480
#define WP    640
#define TOPK  1000
#define CAND_MAX 8192
#define DET_THRESH 0.015f

// ---------------- output layout (floats) ----------------
#define LOGITS_N (B_*COUT*H_*W_)
#define PROB_N   (B_*HP*WP)
#define PROB_OFF (LOGITS_N)
#define NMS_OFF  (PROB_OFF + PROB_N)
#define PRED_OFF (NMS_OFF + PROB_N)

// ---------------- workspace layout (float offsets) ----------------
// WB: conv3 weights, 3 bf16 planes (hi,mid,lo), LINEAR:
//   [ocq4][icc4][tap9][plane3][ocl64][icl32]
#define WB_FN    442368
#define SA_OFF   WB_FN
#define TA_OFF   (SA_OFF + 256)
#define TB_OFF   (TA_OFF + 256)
#define WT1_N    (COUT*CHID)
#define WT1_OFF  (TB_OFF + 128)
#define H_OFF    (WT1_OFF + WT1_N)
#define H_N      (B_*H_*W_*CHID)
#define CAND_OFF (H_OFF + H_N)
#define CNT_OFF  (CAND_OFF + B_*CAND_MAX)
#define CNT_N    (32*32)
#define KTH_OFF  (CNT_OFF + CNT_N)
#define WT_N     (CHID*CIN*9)

// bf16 helpers (RNE)
__device__ __forceinline__ u16 f2bf(float x) {
    unsigned u = __float_as_uint(x);
    return (u16)((u + 0x7fffu + ((u >> 16) & 1u)) >> 16);
}
__device__ __forceinline__ float bf2f(u16 h) {
    return __uint_as_float(((unsigned)h) << 16);
}

// async global->LDS, 16B per lane (lds dest = uniform base + lane*16)
__device__ __forceinline__ void gload_lds16(const float* g, float* l) {
    __builtin_amdgcn_global_load_lds(
        (const __attribute__((address_space(1))) void*)g,
        (__attribute__((address_space(3))) void*)l, 16, 0, 0);
}

#define MFMA16 __builtin_amdgcn_mfma_f32_16x16x32_bf16

// =====================================================================
// K0: prep — WB (conv3 weights 3-plane exact bf16 split, linear),
// sa/ta conv3 BN, tb + wt1 (conv1 folded).
// =====================================================================
__global__ void prep_kernel(const float* __restrict__ wa,
                            const float* __restrict__ ba, const float* __restrict__ ga,
                            const float* __restrict__ bta, const float* __restrict__ ma,
                            const float* __restrict__ va,
                            const float* __restrict__ wb, const float* __restrict__ bb,
                            const float* __restrict__ gb, const float* __restrict__ btb,
                            const float* __restrict__ mb, const float* __restrict__ vb,
                            u16* __restrict__ WBo,
                            float* __restrict__ sa, float* __restrict__ ta,
                            float* __restrict__ tb, float* __restrict__ wt1)
{
    int gid = blockIdx.x * 256 + threadIdx.x;
    if (gid < WT_N) {
        int icl = gid & 31;
        int ocl = (gid >> 5) & 63;
        int rest = gid >> 11;          // [0,144)
        int tap = rest % 9;
        int cq = rest / 9;             // [0,16)
        int icc = cq & 3, ocq = cq >> 2;
        float v = wa[(((ocq * 64 + ocl) * CIN) + icc * 32 + icl) * 9 + tap];
        u16 hh = f2bf(v); float r1 = v - bf2f(hh);
        u16 mm2 = f2bf(r1); float r2 = r1 - bf2f(mm2);
        u16 ll = f2bf(r2);
        size_t base = ((size_t)(((ocq * 4 + icc) * 9 + tap) * 3)) * 2048
                      + ocl * 32 + icl;
        WBo[base] = hh;
        WBo[base + 2048] = mm2;
        WBo[base + 4096] = ll;
    } else if (gid < WT_N + 256) {
        int oc = gid - WT_N;
        float inv = ga[oc] / sqrtf(va[oc] + 1e-5f);
        sa[oc] = inv;
        ta[oc] = (ba[oc] - ma[oc]) * inv + bta[oc];
    } else if (gid < WT_N + 256 + COUT) {
        int oc = gid - (WT_N + 256);
        float inv = gb[oc] / sqrtf(vb[oc] + 1e-5f);
        tb[oc] = (bb[oc] - mb[oc]) * inv + btb[oc];
    } else if (gid < WT_N + 256 + COUT + WT1_N) {
        int i = gid - (WT_N + 256 + COUT);
        int oc = i >> 8;
        float inv = gb[oc] / sqrtf(vb[oc] + 1e-5f);
        wt1[i] = wb[i] * inv;
    }
}

// =====================================================================
// K1: conv3x3 via 6-term split-bf16 MFMA (hh+hm+mh+hl+mm+lh).
// Round-12: A-PREFETCH (issue-early / write-late). icc+1's 14 global
// x-loads issue BEFORE the 9-tap MFMA marathon; convert + ds_write land
// after the next barrier. Single LDS buffer, inner loop = round 9/10
// (bit-identical MFMA order). Round-11 dx-hoist reverted (regressed).
// =====================================================================
__global__ __launch_bounds__(256, 2) void conv3_kernel(const float* __restrict__ x,
                                                       const u16* __restrict__ WB,
                                                       const float* __restrict__ sa,
                                                       const float* __restrict__ ta,
                                                       float* __restrict__ h)
{
    __shared__ __align__(16) u16 xsA[3 * 4536];   // 27216 B: hi, mid, lo planes

    // bijective XCD swizzle: 2400 blocks = 8 * 300
    int d = blockIdx.x;
    int o = (d & 7) * 300 + (d >> 3);
    int tile = o % 75;
    int b = o / 75;
    int ty = tile / 5, tx = tile % 5;
    int y0 = ty * 4, x0 = tx * 16;

    int t = threadIdx.x;
    int wv = __builtin_amdgcn_readfirstlane(t >> 6);   // 0..3 = ocq
    int lane = t & 63;
    int cx = lane & 15;
    int kg = lane >> 4;
    int icl0 = kg * 8;

    const float* xb = x + (size_t)b * CIN * H_ * W_;

    // staging offsets, computed once (reused all 4 icc)
    int goff[14];
#pragma unroll
    for (int j = 0; j < 14; ++j) {
        int e = t + j * 256;
        int go = -1;
        if (e < 3456) {
            int xx = e % 18;
            int yy = (e / 18) % 6;
            int icl = e / 108;
            int gy = y0 + yy - 1, gx = x0 + xx - 1;
            if (gy >= 0 && gy < H_ && gx >= 0 && gx < W_)
                go = icl * (H_ * W_) + gy * W_ + gx;
        }
        goff[j] = go;
    }

    f32x4 acc[4][4];               // [pb(y-row)][f(oc-subtile)] = 64 acc regs
#pragma unroll
    for (int pb = 0; pb < 4; ++pb)
#pragma unroll
        for (int f = 0; f < 4; ++f) acc[pb][f] = (f32x4)(0.f);

    // prologue: load icc=0 slab into registers
    float xr[14];
#pragma unroll
    for (int j = 0; j < 14; ++j)
        xr[j] = (goff[j] >= 0) ? xb[goff[j]] : 0.f;

#pragma unroll 1
    for (int icc = 0; icc < 4; ++icc) {
        __syncthreads();   // all waves done reading xsA (previous icc)
        // write-late: convert prefetched regs -> 3 bf16 planes in LDS
        // row stride 42 u16 (21 dwords, odd) -> staging writes conflict-free
#pragma unroll
        for (int j = 0; j < 14; ++j) {
            int e = t + j * 256;
            if (e < 3456) {
                int xx = e % 18;
                int yy = (e / 18) % 6;
                int icl = e / 108;
                float v = xr[j];
                u16 hh = f2bf(v); float r1 = v - bf2f(hh);
                u16 mm2 = f2bf(r1); float r2 = r1 - bf2f(mm2);
                u16 ll = f2bf(r2);
                int pos = yy * 18 + xx;
                int wu = pos * 42 + (icl ^ (pos & 8));
                xsA[wu] = hh;
                xsA[4536 + wu] = mm2;
                xsA[9072 + wu] = ll;
            }
        }
        __syncthreads();   // writes visible

        // issue-early: icc+1's global loads, in flight across the MFMAs
        if (icc < 3) {
            const float* xc = xb + (icc + 1) * 32 * (H_ * W_);
#pragma unroll
            for (int j = 0; j < 14; ++j)
                if (goff[j] >= 0) xr[j] = xc[goff[j]];
        }

        // 9-tap MFMA marathon (identical order to rounds 9/10)
#pragma unroll 1
        for (int tap = 0; tap < 9; ++tap) {
            int dy = tap / 3, dx = tap - dy * 3;

            const u16* bb_ = WB + ((size_t)(((wv * 4 + icc) * 9 + tap) * 3)) * 2048;
            s16x8 Bh[4], Bm[4], Bl[4];
#pragma unroll
            for (int f = 0; f < 4; ++f) {
                int bu = (f * 16 + cx) * 32 + icl0;
                Bh[f] = *(const s16x8*)&bb_[bu];
                Bm[f] = *(const s16x8*)&bb_[2048 + bu];
                Bl[f] = *(const s16x8*)&bb_[4096 + bu];
            }

#pragma unroll
            for (int pb = 0; pb < 4; ++pb) {
                int pos = (pb + dy) * 18 + cx + dx;
                int au = pos * 42 + (icl0 ^ (pos & 8));
                s16x8 Ah = *(const s16x8*)&xsA[au];
                s16x8 Am = *(const s16x8*)&xsA[4536 + au];
                s16x8 Al = *(const s16x8*)&xsA[9072 + au];
#pragma unroll
                for (int f = 0; f < 4; ++f) {
                    acc[pb][f] = MFMA16(Ah, Bh[f], acc[pb][f], 0, 0, 0);
                    acc[pb][f] = MFMA16(Ah, Bm[f], acc[pb][f], 0, 0, 0);
                    acc[pb][f] = MFMA16(Am, Bh[f], acc[pb][f], 0, 0, 0);
                    acc[pb][f] = MFMA16(Ah, Bl[f], acc[pb][f], 0, 0, 0);
                    acc[pb][f] = MFMA16(Am, Bm[f], acc[pb][f], 0, 0, 0);
                    acc[pb][f] = MFMA16(Al, Bh[f], acc[pb][f], 0, 0, 0);
                }
            }
        }
    }

    // epilogue: C lane map n=lane&15 (oc), m=(lane>>4)*4+r (x-col); BN + ReLU
#pragma unroll
    for (int f = 0; f < 4; ++f) {
        int oc = wv * 64 + f * 16 + cx;
        float s_ = sa[oc], t_ = ta[oc];
#pragma unroll
        for (int pb = 0; pb < 4; ++pb) {
            int y = y0 + pb;
#pragma unroll
            for (int r = 0; r < 4; ++r) {
                int xc2 = x0 + kg * 4 + r;
                size_t addr = ((size_t)(b * (H_ * W_) + y * W_ + xc2)) * CHID + oc;
                h[addr] = fmaxf(fmaf(acc[pb][f][r], s_, t_), 0.f);
            }
        }
    }
}

// =====================================================================
// K2: conv1x1 (256->65) + BN. Round-12: 2 PIXELS PER LANE — halves the
// broadcast weight ds_read_b128 count per output (the measured LDS-
// throughput bound, ~190 us). Weights in 64KB LDS via gload_lds.
// =====================================================================
__global__ __launch_bounds__(256) void conv1_kernel(const float* __restrict__ h,
                                                    const float* __restrict__ wt1,
                                                    const float* __restrict__ tb,
                                                    float* __restrict__ logits,
                                                    float* __restrict__ prob)
{
    __shared__ __align__(16) float ws_[64 * 256];
    int t = threadIdx.x;
    int wave = t >> 6, lane = t & 63;

    for (int k = wave; k < 64; k += 4)
        gload_lds16(wt1 + k * 256 + lane * 4, &ws_[k * 256]);

    int p0 = blockIdx.x * 512 + t;
    int p1 = p0 + 256;
    const float* hp0 = h + (size_t)p0 * CHID;
    const float* hp1 = h + (size_t)p1 * CHID;
    const float* w64g = wt1 + 64 * 256;

    float acc0[COUT], acc1[COUT];
#pragma unroll
    for (int oc = 0; oc < COUT; ++oc) { acc0[oc] = 0.f; acc1[oc] = 0.f; }

    __syncthreads();

#pragma unroll 2
    for (int kc = 0; kc < 32; ++kc) {
        float4 a0 = *(const float4*)(hp0 + kc * 8);
        float4 a1 = *(const float4*)(hp0 + kc * 8 + 4);
        float4 b0 = *(const float4*)(hp1 + kc * 8);
        float4 b1 = *(const float4*)(hp1 + kc * 8 + 4);
        float hv0[8] = {a0.x, a0.y, a0.z, a0.w, a1.x, a1.y, a1.z, a1.w};
        float hv1[8] = {b0.x, b0.y, b0.z, b0.w, b1.x, b1.y, b1.z, b1.w};
        {
            float4 w0 = *(const float4*)(w64g + kc * 8);
            float4 w1 = *(const float4*)(w64g + kc * 8 + 4);
            float wv[8] = {w0.x, w0.y, w0.z, w0.w, w1.x, w1.y, w1.z, w1.w};
            float s0 = acc0[64], s1 = acc1[64];
#pragma unroll
            for (int k = 0; k < 8; ++k) {
                s0 = fmaf(wv[k], hv0[k], s0);
                s1 = fmaf(wv[k], hv1[k], s1);
            }
            acc0[64] = s0; acc1[64] = s1;
        }
#pragma unroll
        for (int oc = 0; oc < 64; ++oc) {
            const float* wr = ws_ + oc * 256 + kc * 8;
            float4 w0 = *(const float4*)wr;
            float4 w1 = *(const float4*)(wr + 4);
            float wv[8] = {w0.x, w0.y, w0.z, w0.w, w1.x, w1.y, w1.z, w1.w};
            float s0 = acc0[oc], s1 = acc1[oc];
#pragma unroll
            for (int k = 0; k < 8; ++k) {
                s0 = fmaf(wv[k], hv0[k], s0);
                s1 = fmaf(wv[k], hv1[k], s1);
            }
            acc0[oc] = s0; acc1[oc] = s1;
        }
    }

#pragma unroll 1
    for (int half = 0; half < 2; ++half) {
        int p = half ? p1 : p0;
        float* accp = half ? acc1 : acc0;
        int b = p / (H_ * W_);
        int yx = p % (H_ * W_);
        int y = yx / W_;
        int xx = yx % W_;

        float v[COUT];
#pragma unroll
        for (int oc = 0; oc < COUT; ++oc)
            v[oc] = accp[oc] + tb[oc];

#pragma unroll
        for (int oc = 0; oc < COUT; ++oc)
            logits[((size_t)(b * COUT + oc)) * (H_ * W_) + yx] = v[oc];

        float* pb = prob + (size_t)b * (HP * WP);
#pragma unroll
        for (int r1 = 0; r1 < 8; ++r1) {
            float4 a0, a1;
            a0.x = v[r1 * 8 + 0]; a0.y = v[r1 * 8 + 1]; a0.z = v[r1 * 8 + 2]; a0.w = v[r1 * 8 + 3];
            a1.x = v[r1 * 8 + 4]; a1.y = v[r1 * 8 + 5]; a1.z = v[r1 * 8 + 6]; a1.w = v[r1 * 8 + 7];
            float* dst = pb + (y * 8 + r1) * WP + xx * 8;
            *(float4*)dst = a0;
            *(float4*)(dst + 4) = a1;
        }
    }
}

// =====================================================================
// K3: 9x9 local-max keep + candidate compaction (1 global atomic/block)
// =====================================================================
__global__ __launch_bounds__(256) void nms_kernel(const float* __restrict__ prob,
                                                  float* __restrict__ keep_out,
                                                  float* __restrict__ cand,
                                                  int* __restrict__ cnt)
{
    __shared__ float xs[40][40];
    __shared__ float rmax[40][32];
    __shared__ float clist[1024];
    __shared__ int csh;
    __shared__ int gbase;

    int bid = blockIdx.x;
    int tx = bid % 20;
    int ty = (bid / 20) % 15;
    int b = bid / 300;
    const float* pb = prob + (size_t)b * (HP * WP);
    int t = threadIdx.x;

    if (t == 0) csh = 0;

    for (int idx = t; idx < 1600; idx += 256) {
        int c = idx % 40, r = idx / 40;
        int gy = ty * 32 - 4 + r;
        int gx = tx * 32 - 4 + c;
        float v = -INFINITY;
        if (gy >= 0 && gy < HP && gx >= 0 && gx < WP) v = pb[gy * WP + gx];
        xs[r][c] = v;
    }
    __syncthreads();

    for (int idx = t; idx < 1280; idx += 256) {
        int c = idx & 31, r = idx >> 5;
        float m = xs[r][c];
#pragma unroll
        for (int d = 1; d < 9; ++d) m = fmaxf(m, xs[r][c + d]);
        rmax[r][c] = m;
    }
    __syncthreads();

    for (int idx = t; idx < 1024; idx += 256) {
        int c = idx & 31, ro = idx >> 5;
        float m = rmax[ro][c];
#pragma unroll
        for (int d = 1; d < 9; ++d) m = fmaxf(m, rmax[ro + d][c]);
        float v = xs[ro + 4][c + 4];
        float keep = (v == m) ? v : 0.f;
        keep_out[(size_t)b * (HP * WP) + (ty * 32 + ro) * WP + tx * 32 + c] = keep;
        if (keep > 0.f) {
            int i = atomicAdd(&csh, 1);
            clist[i] = keep;
        }
    }
    __syncthreads();

    int m = csh;
    if (m > 0) {
        if (t == 0) gbase = atomicAdd(&cnt[b * 32], m);
        __syncthreads();
        int gb = gbase;
        for (int i = t; i < m; i += 256) {
            int dst = gb + i;
            if (dst < CAND_MAX) cand[b * CAND_MAX + dst] = clist[i];
        }
    }
}

// =====================================================================
// K4: exact kth-largest (k=1000) per batch via 4-pass radix select
// =====================================================================
__global__ __launch_bounds__(256) void select_kernel(const float* __restrict__ cand,
                                                     const int* __restrict__ cnt,
                                                     float* __restrict__ kth)
{
    __shared__ unsigned hist[256];
    __shared__ unsigned sh_prefix, sh_K;

    int b = blockIdx.x;
    int t = threadIdx.x;
    int n = cnt[b * 32];
    if (n > CAND_MAX) n = CAND_MAX;
    if (n < TOPK) {
        if (t == 0) kth[b] = 0.f;
        return;
    }
    if (t == 0) { sh_prefix = 0u; sh_K = TOPK; }
    __syncthreads();
    const float* cb = cand + b * CAND_MAX;

    for (int pass = 3; pass >= 0; --pass) {
        hist[t] = 0u;
        __syncthreads();
        unsigned prefix = sh_prefix;
        unsigned himask = (pass == 3) ? 0u : (0xFFFFFFFFu << ((pass + 1) * 8));
        for (int i = t; i < n; i += 256) {
            unsigned u = __float_as_uint(cb[i]);
            if ((u & himask) == prefix)
                atomicAdd(&hist[(u >> (pass * 8)) & 255], 1u);
        }
        __syncthreads();
        if (t == 0) {
            unsigned K = sh_K, cum = 0;
            int sel = 0;
            for (int v2 = 255; v2 >= 0; --v2) {
                if (cum + hist[v2] >= K) { sel = v2; sh_K = K - cum; break; }
                cum += hist[v2];
            }
            sh_prefix = prefix | ((unsigned)sel << (pass * 8));
        }
        __syncthreads();
    }
    if (t == 0) kth[b] = __uint_as_float(sh_prefix);
}

// =====================================================================
// K5: threshold with kth + binarize
// =====================================================================
__global__ __launch_bounds__(256) void thresh_kernel(const float* __restrict__ keep,
                                                     const float* __restrict__ kth,
                                                     float* __restrict__ prob_nms,
                                                     float* __restrict__ pred)
{
    int i4 = blockIdx.x * 256 + threadIdx.x;
    int b = i4 / (HP * WP / 4);
    float tv = kth[b];
    float4 v = ((const float4*)keep)[i4];
    float4 o;
    o.x = (v.x >= tv) ? v.x : 0.f;
    o.y = (v.y >= tv) ? v.y : 0.f;
    o.z = (v.z >= tv) ? v.z : 0.f;
    o.w = (v.w >= tv) ? v.w : 0.f;
    ((float4*)prob_nms)[i4] = o;
    float4 pr;
    pr.x = (o.x >= DET_THRESH) ? 1.f : 0.f;
    pr.y = (o.y >= DET_THRESH) ? 1.f : 0.f;
    pr.z = (o.z >= DET_THRESH) ? 1.f : 0.f;
    pr.w = (o.w >= DET_THRESH) ? 1.f : 0.f;
    ((float4*)pred)[i4] = pr;
}

// =====================================================================
extern "C" void kernel_launch(void* const* d_in, const int* in_sizes, int n_in,
                              void* d_out, int out_size, void* d_ws, size_t ws_size,
                              hipStream_t stream) {
    const float* x   = (const float*)d_in[0];
    const float* wa  = (const float*)d_in[1];
    const float* ba  = (const float*)d_in[2];
    const float* ga  = (const float*)d_in[3];
    const float* bta = (const float*)d_in[4];
    const float* ma  = (const float*)d_in[5];
    const float* va  = (const float*)d_in[6];
    const float* wb  = (const float*)d_in[7];
    const float* bb  = (const float*)d_in[8];
    const float* gb  = (const float*)d_in[9];
    const float* btb = (const float*)d_in[10];
    const float* mb  = (const float*)d_in[11];
    const float* vb  = (const float*)d_in[12];

    float* out = (float*)d_out;
    float* ws  = (float*)d_ws;

    u16*   WB   = (u16*)ws;
    float* sa   = ws + SA_OFF;
    float* ta   = ws + TA_OFF;
    float* tbv  = ws + TB_OFF;
    float* wt1  = ws + WT1_OFF;
    float* h    = ws + H_OFF;
    float* cand = ws + CAND_OFF;
    int*   cnt  = (int*)(ws + CNT_OFF);
    float* kth  = ws + KTH_OFF;

    hipMemsetAsync((void*)cnt, 0, CNT_N * sizeof(int), stream);

    {
        int total = WT_N + 256 + COUT + WT1_N;
        prep_kernel<<<(total + 255) / 256, 256, 0, stream>>>(
            wa, ba, ga, bta, ma, va, wb, bb, gb, btb, mb, vb, WB, sa, ta, tbv, wt1);
    }

    conv3_kernel<<<2400, 256, 0, stream>>>(x, WB, sa, ta, h);

    conv1_kernel<<<(B_ * H_ * W_) / 512, 256, 0, stream>>>(
        h, wt1, tbv, out, out + PROB_OFF);

    nms_kernel<<<32 * 15 * 20, 256, 0, stream>>>(
        out + PROB_OFF, out + NMS_OFF, cand, cnt);

    select_kernel<<<B_, 256, 0, stream>>>(cand, cnt, kth);

    thresh_kernel<<<(PROB_N / 4) / 256, 256, 0, stream>>>(
        out + NMS_OFF, kth, out + NMS_OFF, out + PRED_OFF);
}

// Round 13
// 596.329 us; speedup vs baseline: 1.2206x; 1.1891x over previous
//
#include <hip/hip_runtime.h>
#include <math.h>

typedef short s16x8 __attribute__((ext_vector_type(8)));
typedef float f32x4 __attribute__((ext_vector_type(4)));
typedef unsigned short u16;

// ---------------- problem constants ----------------
#define B_    32
#define CIN   128
#define CHID  256
#define H_    60
#define W_    80
#define COUT  65
#define HP    480
#define WP    640
#define TOPK  1000
#define CAND_MAX 8192
#define DET_THRESH 0.015f

// ---------------- output layout (floats) ----------------
#define LOGITS_N (B_*COUT*H_*W_)
#define PROB_N   (B_*HP*WP)
#define PROB_OFF (LOGITS_N)
#define NMS_OFF  (PROB_OFF + PROB_N)
#define PRED_OFF (NMS_OFF + PROB_N)

// ---------------- workspace layout (float offsets) ----------------
// WB: conv3 weights, 3 bf16 planes, [ocq4][icc4][tap9][plane3][ocl64][icl32]
#define WB_FN    442368
#define SA_OFF   WB_FN
#define TA_OFF   (SA_OFF + 256)
#define TB_OFF   (TA_OFF + 256)
// WB1: conv1 weights for MFMA, 61440 u16 = [ocf5][kc8][plane3][lane64][j8]
#define WB1_FN   30720
#define WB1_OFF  (TB_OFF + 128)
#define H_OFF    (WB1_OFF + WB1_FN)
#define H_N      (B_*H_*W_*CHID)
#define CAND_OFF (H_OFF + H_N)
#define CNT_OFF  (CAND_OFF + B_*CAND_MAX)
#define CNT_N    (32*32)
#define KTH_OFF  (CNT_OFF + CNT_N)
#define WT_N     (CHID*CIN*9)
#define WB1_U16N 61440

// bf16 helpers (RNE)
__device__ __forceinline__ u16 f2bf(float x) {
    unsigned u = __float_as_uint(x);
    return (u16)((u + 0x7fffu + ((u >> 16) & 1u)) >> 16);
}
__device__ __forceinline__ float bf2f(u16 h) {
    return __uint_as_float(((unsigned)h) << 16);
}

#define MFMA16 __builtin_amdgcn_mfma_f32_16x16x32_bf16

// =====================================================================
// K0: prep — WB (conv3 3-plane split), WB1 (conv1 3-plane split, padded
// to 80 oc, per-fragment layout), sa/ta conv3 BN, tb conv1 BN bias.
// =====================================================================
__global__ void prep_kernel(const float* __restrict__ wa,
                            const float* __restrict__ ba, const float* __restrict__ ga,
                            const float* __restrict__ bta, const float* __restrict__ ma,
                            const float* __restrict__ va,
                            const float* __restrict__ wb, const float* __restrict__ bb,
                            const float* __restrict__ gb, const float* __restrict__ btb,
                            const float* __restrict__ mb, const float* __restrict__ vb,
                            u16* __restrict__ WBo,
                            float* __restrict__ sa, float* __restrict__ ta,
                            float* __restrict__ tb, u16* __restrict__ WB1o)
{
    int gid = blockIdx.x * 256 + threadIdx.x;
    if (gid < WT_N) {
        int icl = gid & 31;
        int ocl = (gid >> 5) & 63;
        int rest = gid >> 11;          // [0,144)
        int tap = rest % 9;
        int cq = rest / 9;             // [0,16)
        int icc = cq & 3, ocq = cq >> 2;
        float v = wa[(((ocq * 64 + ocl) * CIN) + icc * 32 + icl) * 9 + tap];
        u16 hh = f2bf(v); float r1 = v - bf2f(hh);
        u16 mm2 = f2bf(r1); float r2 = r1 - bf2f(mm2);
        u16 ll = f2bf(r2);
        size_t base = ((size_t)(((ocq * 4 + icc) * 9 + tap) * 3)) * 2048
                      + ocl * 32 + icl;
        WBo[base] = hh;
        WBo[base + 2048] = mm2;
        WBo[base + 4096] = ll;
    } else if (gid < WT_N + 256) {
        int oc = gid - WT_N;
        float inv = ga[oc] / sqrtf(va[oc] + 1e-5f);
        sa[oc] = inv;
        ta[oc] = (ba[oc] - ma[oc]) * inv + bta[oc];
    } else if (gid < WT_N + 256 + COUT) {
        int oc = gid - (WT_N + 256);
        float inv = gb[oc] / sqrtf(vb[oc] + 1e-5f);
        tb[oc] = (bb[oc] - mb[oc]) * inv + btb[oc];
    } else if (gid < WT_N + 256 + COUT + WB1_U16N) {
        int idx = gid - (WT_N + 256 + COUT);
        int within = idx & 511;
        int j = within & 7;
        int lane = within >> 3;
        int chunk = idx >> 9;          // [0,120)
        int plane = chunk % 3;
        int kc = (chunk / 3) & 7;
        int ocf = chunk / 24;
        int oc = ocf * 16 + (lane & 15);
        int k = kc * 32 + (lane >> 4) * 8 + j;
        float v = 0.f;
        if (oc < COUT) {
            float inv = gb[oc] / sqrtf(vb[oc] + 1e-5f);
            v = wb[oc * CHID + k] * inv;
        }
        u16 hh = f2bf(v); float r1 = v - bf2f(hh);
        u16 mm2 = f2bf(r1); float r2 = r1 - bf2f(mm2);
        u16 ll = f2bf(r2);
        WB1o[idx] = (plane == 0) ? hh : (plane == 1) ? mm2 : ll;
    }
}

// =====================================================================
// K1: conv3x3 via 6-term split-bf16 MFMA (round-12 version, frozen:
// A-prefetch issue-early/write-late, 452 us, MfmaUtil 57%).
// =====================================================================
__global__ __launch_bounds__(256, 2) void conv3_kernel(const float* __restrict__ x,
                                                       const u16* __restrict__ WB,
                                                       const float* __restrict__ sa,
                                                       const float* __restrict__ ta,
                                                       float* __restrict__ h)
{
    __shared__ __align__(16) u16 xsA[3 * 4536];   // 27216 B: hi, mid, lo planes

    // bijective XCD swizzle: 2400 blocks = 8 * 300
    int d = blockIdx.x;
    int o = (d & 7) * 300 + (d >> 3);
    int tile = o % 75;
    int b = o / 75;
    int ty = tile / 5, tx = tile % 5;
    int y0 = ty * 4, x0 = tx * 16;

    int t = threadIdx.x;
    int wv = __builtin_amdgcn_readfirstlane(t >> 6);   // 0..3 = ocq
    int lane = t & 63;
    int cx = lane & 15;
    int kg = lane >> 4;
    int icl0 = kg * 8;

    const float* xb = x + (size_t)b * CIN * H_ * W_;

    int goff[14];
#pragma unroll
    for (int j = 0; j < 14; ++j) {
        int e = t + j * 256;
        int go = -1;
        if (e < 3456) {
            int xx = e % 18;
            int yy = (e / 18) % 6;
            int icl = e / 108;
            int gy = y0 + yy - 1, gx = x0 + xx - 1;
            if (gy >= 0 && gy < H_ && gx >= 0 && gx < W_)
                go = icl * (H_ * W_) + gy * W_ + gx;
        }
        goff[j] = go;
    }

    f32x4 acc[4][4];
#pragma unroll
    for (int pb = 0; pb < 4; ++pb)
#pragma unroll
        for (int f = 0; f < 4; ++f) acc[pb][f] = (f32x4)(0.f);

    float xr[14];
#pragma unroll
    for (int j = 0; j < 14; ++j)
        xr[j] = (goff[j] >= 0) ? xb[goff[j]] : 0.f;

#pragma unroll 1
    for (int icc = 0; icc < 4; ++icc) {
        __syncthreads();
#pragma unroll
        for (int j = 0; j < 14; ++j) {
            int e = t + j * 256;
            if (e < 3456) {
                int xx = e % 18;
                int yy = (e / 18) % 6;
                int icl = e / 108;
                float v = xr[j];
                u16 hh = f2bf(v); float r1 = v - bf2f(hh);
                u16 mm2 = f2bf(r1); float r2 = r1 - bf2f(mm2);
                u16 ll = f2bf(r2);
                int pos = yy * 18 + xx;
                int wu = pos * 42 + (icl ^ (pos & 8));
                xsA[wu] = hh;
                xsA[4536 + wu] = mm2;
                xsA[9072 + wu] = ll;
            }
        }
        __syncthreads();

        if (icc < 3) {
            const float* xc = xb + (icc + 1) * 32 * (H_ * W_);
#pragma unroll
            for (int j = 0; j < 14; ++j)
                if (goff[j] >= 0) xr[j] = xc[goff[j]];
        }

#pragma unroll 1
        for (int tap = 0; tap < 9; ++tap) {
            int dy = tap / 3, dx = tap - dy * 3;

            const u16* bb_ = WB + ((size_t)(((wv * 4 + icc) * 9 + tap) * 3)) * 2048;
            s16x8 Bh[4], Bm[4], Bl[4];
#pragma unroll
            for (int f = 0; f < 4; ++f) {
                int bu = (f * 16 + cx) * 32 + icl0;
                Bh[f] = *(const s16x8*)&bb_[bu];
                Bm[f] = *(const s16x8*)&bb_[2048 + bu];
                Bl[f] = *(const s16x8*)&bb_[4096 + bu];
            }

#pragma unroll
            for (int pb = 0; pb < 4; ++pb) {
                int pos = (pb + dy) * 18 + cx + dx;
                int au = pos * 42 + (icl0 ^ (pos & 8));
                s16x8 Ah = *(const s16x8*)&xsA[au];
                s16x8 Am = *(const s16x8*)&xsA[4536 + au];
                s16x8 Al = *(const s16x8*)&xsA[9072 + au];
#pragma unroll
                for (int f = 0; f < 4; ++f) {
                    acc[pb][f] = MFMA16(Ah, Bh[f], acc[pb][f], 0, 0, 0);
                    acc[pb][f] = MFMA16(Ah, Bm[f], acc[pb][f], 0, 0, 0);
                    acc[pb][f] = MFMA16(Am, Bh[f], acc[pb][f], 0, 0, 0);
                    acc[pb][f] = MFMA16(Ah, Bl[f], acc[pb][f], 0, 0, 0);
                    acc[pb][f] = MFMA16(Am, Bm[f], acc[pb][f], 0, 0, 0);
                    acc[pb][f] = MFMA16(Al, Bh[f], acc[pb][f], 0, 0, 0);
                }
            }
        }
    }

#pragma unroll
    for (int f = 0; f < 4; ++f) {
        int oc = wv * 64 + f * 16 + cx;
        float s_ = sa[oc], t_ = ta[oc];
#pragma unroll
        for (int pb = 0; pb < 4; ++pb) {
            int y = y0 + pb;
#pragma unroll
            for (int r = 0; r < 4; ++r) {
                int xc2 = x0 + kg * 4 + r;
                size_t addr = ((size_t)(b * (H_ * W_) + y * W_ + xc2)) * CHID + oc;
                h[addr] = fmaxf(fmaf(acc[pb][f][r], s_, t_), 0.f);
            }
        }
    }
}

// =====================================================================
// K2: conv1x1 as MFMA GEMM (6-term split, same scheme as conv3).
// A = h (channel-last -> contiguous 32B/lane from GLOBAL, no LDS).
// B = WB1 per-fragment packed (L2-resident, 16B/lane coalesced).
// Wave = 32 px x 80 oc (65 padded). Block = 128 px. No barriers.
// =====================================================================
__global__ __launch_bounds__(256) void conv1_kernel(const float* __restrict__ h,
                                                    const u16* __restrict__ WB1,
                                                    const float* __restrict__ tb,
                                                    float* __restrict__ logits,
                                                    float* __restrict__ prob)
{
    int t = threadIdx.x;
    int wv = t >> 6;
    int lane = t & 63;
    int px0 = blockIdx.x * 128 + wv * 32;
    int k0l = (lane >> 4) * 8;

    const float* hp0 = h + (size_t)(px0 + (lane & 15)) * CHID + k0l;
    const float* hp1 = hp0 + 16 * CHID;

    f32x4 acc0[5], acc1[5];
#pragma unroll
    for (int f = 0; f < 5; ++f) { acc0[f] = (f32x4)(0.f); acc1[f] = (f32x4)(0.f); }

#pragma unroll 1
    for (int kc = 0; kc < 8; ++kc) {
        s16x8 Ah0, Am0, Al0, Ah1, Am1, Al1;
        {
            float4 a0 = *(const float4*)(hp0 + kc * 32);
            float4 a1 = *(const float4*)(hp0 + kc * 32 + 4);
            float av[8] = {a0.x, a0.y, a0.z, a0.w, a1.x, a1.y, a1.z, a1.w};
#pragma unroll
            for (int j = 0; j < 8; ++j) {
                u16 hh = f2bf(av[j]); float r1 = av[j] - bf2f(hh);
                u16 mm2 = f2bf(r1); float r2 = r1 - bf2f(mm2);
                Ah0[j] = (short)hh; Am0[j] = (short)mm2; Al0[j] = (short)f2bf(r2);
            }
        }
        {
            float4 a0 = *(const float4*)(hp1 + kc * 32);
            float4 a1 = *(const float4*)(hp1 + kc * 32 + 4);
            float av[8] = {a0.x, a0.y, a0.z, a0.w, a1.x, a1.y, a1.z, a1.w};
#pragma unroll
            for (int j = 0; j < 8; ++j) {
                u16 hh = f2bf(av[j]); float r1 = av[j] - bf2f(hh);
                u16 mm2 = f2bf(r1); float r2 = r1 - bf2f(mm2);
                Ah1[j] = (short)hh; Am1[j] = (short)mm2; Al1[j] = (short)f2bf(r2);
            }
        }
#pragma unroll
        for (int f = 0; f < 5; ++f) {
            const u16* bbase = WB1 + ((size_t)(f * 8 + kc) * 3) * 512 + lane * 8;
            s16x8 Bh = *(const s16x8*)bbase;
            s16x8 Bm = *(const s16x8*)(bbase + 512);
            s16x8 Bl = *(const s16x8*)(bbase + 1024);
            acc0[f] = MFMA16(Ah0, Bh, acc0[f], 0, 0, 0);
            acc0[f] = MFMA16(Ah0, Bm, acc0[f], 0, 0, 0);
            acc0[f] = MFMA16(Am0, Bh, acc0[f], 0, 0, 0);
            acc0[f] = MFMA16(Ah0, Bl, acc0[f], 0, 0, 0);
            acc0[f] = MFMA16(Am0, Bm, acc0[f], 0, 0, 0);
            acc0[f] = MFMA16(Al0, Bh, acc0[f], 0, 0, 0);
            acc1[f] = MFMA16(Ah1, Bh, acc1[f], 0, 0, 0);
            acc1[f] = MFMA16(Ah1, Bm, acc1[f], 0, 0, 0);
            acc1[f] = MFMA16(Am1, Bh, acc1[f], 0, 0, 0);
            acc1[f] = MFMA16(Ah1, Bl, acc1[f], 0, 0, 0);
            acc1[f] = MFMA16(Am1, Bm, acc1[f], 0, 0, 0);
            acc1[f] = MFMA16(Al1, Bh, acc1[f], 0, 0, 0);
        }
    }

    // epilogue: C map n(oc)=lane&15, m(px)=(lane>>4)*4+r
#define C1_EPI(ACC, PXB)                                                        \
    {                                                                           \
        int pxm = (PXB) + (lane >> 4) * 4;                                      \
        _Pragma("unroll")                                                       \
        for (int f = 0; f < 5; ++f) {                                           \
            int oc = f * 16 + (lane & 15);                                      \
            if (oc < COUT) {                                                    \
                float tbv = tb[oc];                                             \
                _Pragma("unroll")                                               \
                for (int r = 0; r < 4; ++r) {                                   \
                    int p = pxm + r;                                            \
                    int b = p / (H_ * W_);                                      \
                    int yx = p % (H_ * W_);                                     \
                    float val = ACC[f][r] + tbv;                                \
                    logits[((size_t)(b * COUT + oc)) * (H_ * W_) + yx] = val;   \
                    if (oc < 64) {                                              \
                        int y = yx / W_, xx = yx % W_;                          \
                        prob[(size_t)b * (HP * WP) + (y * 8 + (oc >> 3)) * WP   \
                             + xx * 8 + (oc & 7)] = val;                        \
                    }                                                           \
                }                                                               \
            }                                                                   \
        }                                                                       \
    }

    C1_EPI(acc0, px0)
    C1_EPI(acc1, px0 + 16)
#undef C1_EPI
}

// =====================================================================
// K3: 9x9 local-max keep + candidate compaction (1 global atomic/block)
// =====================================================================
__global__ __launch_bounds__(256) void nms_kernel(const float* __restrict__ prob,
                                                  float* __restrict__ keep_out,
                                                  float* __restrict__ cand,
                                                  int* __restrict__ cnt)
{
    __shared__ float xs[40][40];
    __shared__ float rmax[40][32];
    __shared__ float clist[1024];
    __shared__ int csh;
    __shared__ int gbase;

    int bid = blockIdx.x;
    int tx = bid % 20;
    int ty = (bid / 20) % 15;
    int b = bid / 300;
    const float* pb = prob + (size_t)b * (HP * WP);
    int t = threadIdx.x;

    if (t == 0) csh = 0;

    for (int idx = t; idx < 1600; idx += 256) {
        int c = idx % 40, r = idx / 40;
        int gy = ty * 32 - 4 + r;
        int gx = tx * 32 - 4 + c;
        float v = -INFINITY;
        if (gy >= 0 && gy < HP && gx >= 0 && gx < WP) v = pb[gy * WP + gx];
        xs[r][c] = v;
    }
    __syncthreads();

    for (int idx = t; idx < 1280; idx += 256) {
        int c = idx & 31, r = idx >> 5;
        float m = xs[r][c];
#pragma unroll
        for (int d = 1; d < 9; ++d) m = fmaxf(m, xs[r][c + d]);
        rmax[r][c] = m;
    }
    __syncthreads();

    for (int idx = t; idx < 1024; idx += 256) {
        int c = idx & 31, ro = idx >> 5;
        float m = rmax[ro][c];
#pragma unroll
        for (int d = 1; d < 9; ++d) m = fmaxf(m, rmax[ro + d][c]);
        float v = xs[ro + 4][c + 4];
        float keep = (v == m) ? v : 0.f;
        keep_out[(size_t)b * (HP * WP) + (ty * 32 + ro) * WP + tx * 32 + c] = keep;
        if (keep > 0.f) {
            int i = atomicAdd(&csh, 1);
            clist[i] = keep;
        }
    }
    __syncthreads();

    int m = csh;
    if (m > 0) {
        if (t == 0) gbase = atomicAdd(&cnt[b * 32], m);
        __syncthreads();
        int gb = gbase;
        for (int i = t; i < m; i += 256) {
            int dst = gb + i;
            if (dst < CAND_MAX) cand[b * CAND_MAX + dst] = clist[i];
        }
    }
}

// =====================================================================
// K4: exact kth-largest (k=1000) per batch via 4-pass radix select
// =====================================================================
__global__ __launch_bounds__(256) void select_kernel(const float* __restrict__ cand,
                                                     const int* __restrict__ cnt,
                                                     float* __restrict__ kth)
{
    __shared__ unsigned hist[256];
    __shared__ unsigned sh_prefix, sh_K;

    int b = blockIdx.x;
    int t = threadIdx.x;
    int n = cnt[b * 32];
    if (n > CAND_MAX) n = CAND_MAX;
    if (n < TOPK) {
        if (t == 0) kth[b] = 0.f;
        return;
    }
    if (t == 0) { sh_prefix = 0u; sh_K = TOPK; }
    __syncthreads();
    const float* cb = cand + b * CAND_MAX;

    for (int pass = 3; pass >= 0; --pass) {
        hist[t] = 0u;
        __syncthreads();
        unsigned prefix = sh_prefix;
        unsigned himask = (pass == 3) ? 0u : (0xFFFFFFFFu << ((pass + 1) * 8));
        for (int i = t; i < n; i += 256) {
            unsigned u = __float_as_uint(cb[i]);
            if ((u & himask) == prefix)
                atomicAdd(&hist[(u >> (pass * 8)) & 255], 1u);
        }
        __syncthreads();
        if (t == 0) {
            unsigned K = sh_K, cum = 0;
            int sel = 0;
            for (int v2 = 255; v2 >= 0; --v2) {
                if (cum + hist[v2] >= K) { sel = v2; sh_K = K - cum; break; }
                cum += hist[v2];
            }
            sh_prefix = prefix | ((unsigned)sel << (pass * 8));
        }
        __syncthreads();
    }
    if (t == 0) kth[b] = __uint_as_float(sh_prefix);
}

// =====================================================================
// K5: threshold with kth + binarize
// =====================================================================
__global__ __launch_bounds__(256) void thresh_kernel(const float* __restrict__ keep,
                                                     const float* __restrict__ kth,
                                                     float* __restrict__ prob_nms,
                                                     float* __restrict__ pred)
{
    int i4 = blockIdx.x * 256 + threadIdx.x;
    int b = i4 / (HP * WP / 4);
    float tv = kth[b];
    float4 v = ((const float4*)keep)[i4];
    float4 o;
    o.x = (v.x >= tv) ? v.x : 0.f;
    o.y = (v.y >= tv) ? v.y : 0.f;
    o.z = (v.z >= tv) ? v.z : 0.f;
    o.w = (v.w >= tv) ? v.w : 0.f;
    ((float4*)prob_nms)[i4] = o;
    float4 pr;
    pr.x = (o.x >= DET_THRESH) ? 1.f : 0.f;
    pr.y = (o.y >= DET_THRESH) ? 1.f : 0.f;
    pr.z = (o.z >= DET_THRESH) ? 1.f : 0.f;
    pr.w = (o.w >= DET_THRESH) ? 1.f : 0.f;
    ((float4*)pred)[i4] = pr;
}

// =====================================================================
extern "C" void kernel_launch(void* const* d_in, const int* in_sizes, int n_in,
                              void* d_out, int out_size, void* d_ws, size_t ws_size,
                              hipStream_t stream) {
    const float* x   = (const float*)d_in[0];
    const float* wa  = (const float*)d_in[1];
    const float* ba  = (const float*)d_in[2];
    const float* ga  = (const float*)d_in[3];
    const float* bta = (const float*)d_in[4];
    const float* ma  = (const float*)d_in[5];
    const float* va  = (const float*)d_in[6];
    const float* wb  = (const float*)d_in[7];
    const float* bb  = (const float*)d_in[8];
    const float* gb  = (const float*)d_in[9];
    const float* btb = (const float*)d_in[10];
    const float* mb  = (const float*)d_in[11];
    const float* vb  = (const float*)d_in[12];

    float* out = (float*)d_out;
    float* ws  = (float*)d_ws;

    u16*   WB   = (u16*)ws;
    float* sa   = ws + SA_OFF;
    float* ta   = ws + TA_OFF;
    float* tbv  = ws + TB_OFF;
    u16*   WB1  = (u16*)(ws + WB1_OFF);
    float* h    = ws + H_OFF;
    float* cand = ws + CAND_OFF;
    int*   cnt  = (int*)(ws + CNT_OFF);
    float* kth  = ws + KTH_OFF;

    hipMemsetAsync((void*)cnt, 0, CNT_N * sizeof(int), stream);

    {
        int total = WT_N + 256 + COUT + WB1_U16N;
        prep_kernel<<<(total + 255) / 256, 256, 0, stream>>>(
            wa, ba, ga, bta, ma, va, wb, bb, gb, btb, mb, vb, WB, sa, ta, tbv, WB1);
    }

    conv3_kernel<<<2400, 256, 0, stream>>>(x, WB, sa, ta, h);

    conv1_kernel<<<(B_ * H_ * W_) / 128, 256, 0, stream>>>(
        h, WB1, tbv, out, out + PROB_OFF);

    nms_kernel<<<32 * 15 * 20, 256, 0, stream>>>(
        out + PROB_OFF, out + NMS_OFF, cand, cnt);

    select_kernel<<<B_, 256, 0, stream>>>(cand, cnt, kth);

    thresh_kernel<<<(PROB_N / 4) / 256, 256, 0, stream>>>(
        out + NMS_OFF, kth, out + NMS_OFF, out + PRED_OFF);
}

// Round 14
// 592.138 us; speedup vs baseline: 1.2292x; 1.0071x over previous
//
#include <hip/hip_runtime.h>
#include <math.h>

typedef short s16x8 __attribute__((ext_vector_type(8)));
typedef float f32x4 __attribute__((ext_vector_type(4)));
typedef unsigned short u16;

// ---------------- problem constants ----------------
#define B_    32
#define CIN   128
#define CHID  256
#define H_    60
#define W_    80
#define COUT  65
#define HP    480
#define WP    640
#define TOPK  1000
#define CAND_MAX 8192
#define DET_THRESH 0.015f

// ---------------- output layout (floats) ----------------
#define LOGITS_N (B_*COUT*H_*W_)
#define PROB_N   (B_*HP*WP)
#define PROB_OFF (LOGITS_N)
#define NMS_OFF  (PROB_OFF + PROB_N)
#define PRED_OFF (NMS_OFF + PROB_N)

// ---------------- workspace layout (float offsets) ----------------
// WB: conv3 weights, 3 bf16 planes, [ocq4][icc4][tap9][plane3][ocl64][icl32]
#define WB_FN    442368
#define SA_OFF   WB_FN
#define TA_OFF   (SA_OFF + 256)
#define TB_OFF   (TA_OFF + 256)
// WB1: conv1 weights for MFMA, 61440 u16 = [ocf5][kc8][plane3][lane64][j8]
#define WB1_FN   30720
#define WB1_OFF  (TB_OFF + 128)
#define H_OFF    (WB1_OFF + WB1_FN)
#define H_N      (B_*H_*W_*CHID)
#define CAND_OFF (H_OFF + H_N)
#define CNT_OFF  (CAND_OFF + B_*CAND_MAX)
#define CNT_N    (32*32)
#define KTH_OFF  (CNT_OFF + CNT_N)
#define WT_N     (CHID*CIN*9)
#define WB1_U16N 61440

// conv3 LDS A-layout: unit (pos,kg) of 8 u16 at dword 29*pos + 8*kg.
// Row stride 58 u16 (29 dw, odd); plane stride 6264 u16 (108 rows).
// Frag-read bank balance: starts {29*cx + 8*kg} mod 32 hit every bank
// exactly 8x (the b128 floor) -> zero excess conflicts. Staging writes
// stride 29 dw (odd) -> all 32 banks, 2 lanes/bank = free.
#define AROW  58
#define APLN  6264

// bf16 helpers (RNE)
__device__ __forceinline__ u16 f2bf(float x) {
    unsigned u = __float_as_uint(x);
    return (u16)((u + 0x7fffu + ((u >> 16) & 1u)) >> 16);
}
__device__ __forceinline__ float bf2f(u16 h) {
    return __uint_as_float(((unsigned)h) << 16);
}

#define MFMA16 __builtin_amdgcn_mfma_f32_16x16x32_bf16

// =====================================================================
// K0: prep — WB (conv3 3-plane split), WB1 (conv1 3-plane split, padded
// to 80 oc, per-fragment layout), sa/ta conv3 BN, tb conv1 BN bias.
// =====================================================================
__global__ void prep_kernel(const float* __restrict__ wa,
                            const float* __restrict__ ba, const float* __restrict__ ga,
                            const float* __restrict__ bta, const float* __restrict__ ma,
                            const float* __restrict__ va,
                            const float* __restrict__ wb, const float* __restrict__ bb,
                            const float* __restrict__ gb, const float* __restrict__ btb,
                            const float* __restrict__ mb, const float* __restrict__ vb,
                            u16* __restrict__ WBo,
                            float* __restrict__ sa, float* __restrict__ ta,
                            float* __restrict__ tb, u16* __restrict__ WB1o)
{
    int gid = blockIdx.x * 256 + threadIdx.x;
    if (gid < WT_N) {
        int icl = gid & 31;
        int ocl = (gid >> 5) & 63;
        int rest = gid >> 11;          // [0,144)
        int tap = rest % 9;
        int cq = rest / 9;             // [0,16)
        int icc = cq & 3, ocq = cq >> 2;
        float v = wa[(((ocq * 64 + ocl) * CIN) + icc * 32 + icl) * 9 + tap];
        u16 hh = f2bf(v); float r1 = v - bf2f(hh);
        u16 mm2 = f2bf(r1); float r2 = r1 - bf2f(mm2);
        u16 ll = f2bf(r2);
        size_t base = ((size_t)(((ocq * 4 + icc) * 9 + tap) * 3)) * 2048
                      + ocl * 32 + icl;
        WBo[base] = hh;
        WBo[base + 2048] = mm2;
        WBo[base + 4096] = ll;
    } else if (gid < WT_N + 256) {
        int oc = gid - WT_N;
        float inv = ga[oc] / sqrtf(va[oc] + 1e-5f);
        sa[oc] = inv;
        ta[oc] = (ba[oc] - ma[oc]) * inv + bta[oc];
    } else if (gid < WT_N + 256 + COUT) {
        int oc = gid - (WT_N + 256);
        float inv = gb[oc] / sqrtf(vb[oc] + 1e-5f);
        tb[oc] = (bb[oc] - mb[oc]) * inv + btb[oc];
    } else if (gid < WT_N + 256 + COUT + WB1_U16N) {
        int idx = gid - (WT_N + 256 + COUT);
        int within = idx & 511;
        int j = within & 7;
        int lane = within >> 3;
        int chunk = idx >> 9;          // [0,120)
        int plane = chunk % 3;
        int kc = (chunk / 3) & 7;
        int ocf = chunk / 24;
        int oc = ocf * 16 + (lane & 15);
        int k = kc * 32 + (lane >> 4) * 8 + j;
        float v = 0.f;
        if (oc < COUT) {
            float inv = gb[oc] / sqrtf(vb[oc] + 1e-5f);
            v = wb[oc * CHID + k] * inv;
        }
        u16 hh = f2bf(v); float r1 = v - bf2f(hh);
        u16 mm2 = f2bf(r1); float r2 = r1 - bf2f(mm2);
        u16 ll = f2bf(r2);
        WB1o[idx] = (plane == 0) ? hh : (plane == 1) ? mm2 : ll;
    }
}

// =====================================================================
// K1: conv3x3 via 6-term split-bf16 MFMA (hh+hm+mh+hl+mm+lh).
// Round-14: perfectly-banked A layout (AROW=58 u16, unit kg*16) —
// frag reads hit every bank exactly 8x (floor), staging writes free.
// A-prefetch (issue-early / write-late) kept from round 12.
// =====================================================================
__global__ __launch_bounds__(256, 2) void conv3_kernel(const float* __restrict__ x,
                                                       const u16* __restrict__ WB,
                                                       const float* __restrict__ sa,
                                                       const float* __restrict__ ta,
                                                       float* __restrict__ h)
{
    __shared__ __align__(16) u16 xsA[3 * APLN];   // 37584 B: hi, mid, lo planes

    // bijective XCD swizzle: 2400 blocks = 8 * 300
    int d = blockIdx.x;
    int o = (d & 7) * 300 + (d >> 3);
    int tile = o % 75;
    int b = o / 75;
    int ty = tile / 5, tx = tile % 5;
    int y0 = ty * 4, x0 = tx * 16;

    int t = threadIdx.x;
    int wv = __builtin_amdgcn_readfirstlane(t >> 6);   // 0..3 = ocq
    int lane = t & 63;
    int cx = lane & 15;
    int kg = lane >> 4;
    int icl0 = kg * 8;

    const float* xb = x + (size_t)b * CIN * H_ * W_;

    // staging offsets, computed once (x-fastest mapping -> coalesced)
    int goff[14];
#pragma unroll
    for (int j = 0; j < 14; ++j) {
        int e = t + j * 256;
        int go = -1;
        if (e < 3456) {
            int xx = e % 18;
            int yy = (e / 18) % 6;
            int icl = e / 108;
            int gy = y0 + yy - 1, gx = x0 + xx - 1;
            if (gy >= 0 && gy < H_ && gx >= 0 && gx < W_)
                go = icl * (H_ * W_) + gy * W_ + gx;
        }
        goff[j] = go;
    }

    f32x4 acc[4][4];
#pragma unroll
    for (int pb = 0; pb < 4; ++pb)
#pragma unroll
        for (int f = 0; f < 4; ++f) acc[pb][f] = (f32x4)(0.f);

    // prologue: load icc=0 slab into registers
    float xr[14];
#pragma unroll
    for (int j = 0; j < 14; ++j)
        xr[j] = (goff[j] >= 0) ? xb[goff[j]] : 0.f;

#pragma unroll 1
    for (int icc = 0; icc < 4; ++icc) {
        __syncthreads();   // all waves done reading xsA (previous icc)
        // write-late: convert prefetched regs -> 3 bf16 planes in LDS
#pragma unroll
        for (int j = 0; j < 14; ++j) {
            int e = t + j * 256;
            if (e < 3456) {
                int xx = e % 18;
                int yy = (e / 18) % 6;
                int icl = e / 108;
                float v = xr[j];
                u16 hh = f2bf(v); float r1 = v - bf2f(hh);
                u16 mm2 = f2bf(r1); float r2 = r1 - bf2f(mm2);
                u16 ll = f2bf(r2);
                int pos = yy * 18 + xx;
                int wu = pos * AROW + ((icl >> 3) << 4) + (icl & 7);
                xsA[wu] = hh;
                xsA[APLN + wu] = mm2;
                xsA[2 * APLN + wu] = ll;
            }
        }
        __syncthreads();   // writes visible

        // issue-early: icc+1's global loads, in flight across the MFMAs
        if (icc < 3) {
            const float* xc = xb + (icc + 1) * 32 * (H_ * W_);
#pragma unroll
            for (int j = 0; j < 14; ++j)
                if (goff[j] >= 0) xr[j] = xc[goff[j]];
        }

        // 9-tap MFMA marathon (identical order to rounds 9-13)
#pragma unroll 1
        for (int tap = 0; tap < 9; ++tap) {
            int dy = tap / 3, dx = tap - dy * 3;

            const u16* bb_ = WB + ((size_t)(((wv * 4 + icc) * 9 + tap) * 3)) * 2048;
            s16x8 Bh[4], Bm[4], Bl[4];
#pragma unroll
            for (int f = 0; f < 4; ++f) {
                int bu = (f * 16 + cx) * 32 + icl0;
                Bh[f] = *(const s16x8*)&bb_[bu];
                Bm[f] = *(const s16x8*)&bb_[2048 + bu];
                Bl[f] = *(const s16x8*)&bb_[4096 + bu];
            }

#pragma unroll
            for (int pb = 0; pb < 4; ++pb) {
                int pos = (pb + dy) * 18 + cx + dx;
                int au = pos * AROW + (kg << 4);
                s16x8 Ah = *(const s16x8*)&xsA[au];
                s16x8 Am = *(const s16x8*)&xsA[APLN + au];
                s16x8 Al = *(const s16x8*)&xsA[2 * APLN + au];
#pragma unroll
                for (int f = 0; f < 4; ++f) {
                    acc[pb][f] = MFMA16(Ah, Bh[f], acc[pb][f], 0, 0, 0);
                    acc[pb][f] = MFMA16(Ah, Bm[f], acc[pb][f], 0, 0, 0);
                    acc[pb][f] = MFMA16(Am, Bh[f], acc[pb][f], 0, 0, 0);
                    acc[pb][f] = MFMA16(Ah, Bl[f], acc[pb][f], 0, 0, 0);
                    acc[pb][f] = MFMA16(Am, Bm[f], acc[pb][f], 0, 0, 0);
                    acc[pb][f] = MFMA16(Al, Bh[f], acc[pb][f], 0, 0, 0);
                }
            }
        }
    }

    // epilogue: C lane map n=lane&15 (oc), m=(lane>>4)*4+r (x-col); BN + ReLU
#pragma unroll
    for (int f = 0; f < 4; ++f) {
        int oc = wv * 64 + f * 16 + cx;
        float s_ = sa[oc], t_ = ta[oc];
#pragma unroll
        for (int pb = 0; pb < 4; ++pb) {
            int y = y0 + pb;
#pragma unroll
            for (int r = 0; r < 4; ++r) {
                int xc2 = x0 + kg * 4 + r;
                size_t addr = ((size_t)(b * (H_ * W_) + y * W_ + xc2)) * CHID + oc;
                h[addr] = fmaxf(fmaf(acc[pb][f][r], s_, t_), 0.f);
            }
        }
    }
}

// =====================================================================
// K2: conv1x1 as MFMA GEMM (6-term split). A = h from global (no LDS),
// B = WB1 per-fragment packed (L2-resident). Wave = 32 px x 80 oc.
// =====================================================================
__global__ __launch_bounds__(256) void conv1_kernel(const float* __restrict__ h,
                                                    const u16* __restrict__ WB1,
                                                    const float* __restrict__ tb,
                                                    float* __restrict__ logits,
                                                    float* __restrict__ prob)
{
    int t = threadIdx.x;
    int wv = t >> 6;
    int lane = t & 63;
    int px0 = blockIdx.x * 128 + wv * 32;
    int k0l = (lane >> 4) * 8;

    const float* hp0 = h + (size_t)(px0 + (lane & 15)) * CHID + k0l;
    const float* hp1 = hp0 + 16 * CHID;

    f32x4 acc0[5], acc1[5];
#pragma unroll
    for (int f = 0; f < 5; ++f) { acc0[f] = (f32x4)(0.f); acc1[f] = (f32x4)(0.f); }

#pragma unroll 1
    for (int kc = 0; kc < 8; ++kc) {
        s16x8 Ah0, Am0, Al0, Ah1, Am1, Al1;
        {
            float4 a0 = *(const float4*)(hp0 + kc * 32);
            float4 a1 = *(const float4*)(hp0 + kc * 32 + 4);
            float av[8] = {a0.x, a0.y, a0.z, a0.w, a1.x, a1.y, a1.z, a1.w};
#pragma unroll
            for (int j = 0; j < 8; ++j) {
                u16 hh = f2bf(av[j]); float r1 = av[j] - bf2f(hh);
                u16 mm2 = f2bf(r1); float r2 = r1 - bf2f(mm2);
                Ah0[j] = (short)hh; Am0[j] = (short)mm2; Al0[j] = (short)f2bf(r2);
            }
        }
        {
            float4 a0 = *(const float4*)(hp1 + kc * 32);
            float4 a1 = *(const float4*)(hp1 + kc * 32 + 4);
            float av[8] = {a0.x, a0.y, a0.z, a0.w, a1.x, a1.y, a1.z, a1.w};
#pragma unroll
            for (int j = 0; j < 8; ++j) {
                u16 hh = f2bf(av[j]); float r1 = av[j] - bf2f(hh);
                u16 mm2 = f2bf(r1); float r2 = r1 - bf2f(mm2);
                Ah1[j] = (short)hh; Am1[j] = (short)mm2; Al1[j] = (short)f2bf(r2);
            }
        }
#pragma unroll
        for (int f = 0; f < 5; ++f) {
            const u16* bbase = WB1 + ((size_t)(f * 8 + kc) * 3) * 512 + lane * 8;
            s16x8 Bh = *(const s16x8*)bbase;
            s16x8 Bm = *(const s16x8*)(bbase + 512);
            s16x8 Bl = *(const s16x8*)(bbase + 1024);
            acc0[f] = MFMA16(Ah0, Bh, acc0[f], 0, 0, 0);
            acc0[f] = MFMA16(Ah0, Bm, acc0[f], 0, 0, 0);
            acc0[f] = MFMA16(Am0, Bh, acc0[f], 0, 0, 0);
            acc0[f] = MFMA16(Ah0, Bl, acc0[f], 0, 0, 0);
            acc0[f] = MFMA16(Am0, Bm, acc0[f], 0, 0, 0);
            acc0[f] = MFMA16(Al0, Bh, acc0[f], 0, 0, 0);
            acc1[f] = MFMA16(Ah1, Bh, acc1[f], 0, 0, 0);
            acc1[f] = MFMA16(Ah1, Bm, acc1[f], 0, 0, 0);
            acc1[f] = MFMA16(Am1, Bh, acc1[f], 0, 0, 0);
            acc1[f] = MFMA16(Ah1, Bl, acc1[f], 0, 0, 0);
            acc1[f] = MFMA16(Am1, Bm, acc1[f], 0, 0, 0);
            acc1[f] = MFMA16(Al1, Bh, acc1[f], 0, 0, 0);
        }
    }

    // epilogue: C map n(oc)=lane&15, m(px)=(lane>>4)*4+r
#define C1_EPI(ACC, PXB)                                                        \
    {                                                                           \
        int pxm = (PXB) + (lane >> 4) * 4;                                      \
        _Pragma("unroll")                                                       \
        for (int f = 0; f < 5; ++f) {                                           \
            int oc = f * 16 + (lane & 15);                                      \
            if (oc < COUT) {                                                    \
                float tbv = tb[oc];                                             \
                _Pragma("unroll")                                               \
                for (int r = 0; r < 4; ++r) {                                   \
                    int p = pxm + r;                                            \
                    int b = p / (H_ * W_);                                      \
                    int yx = p % (H_ * W_);                                     \
                    float val = ACC[f][r] + tbv;                                \
                    logits[((size_t)(b * COUT + oc)) * (H_ * W_) + yx] = val;   \
                    if (oc < 64) {                                              \
                        int y = yx / W_, xx = yx % W_;                          \
                        prob[(size_t)b * (HP * WP) + (y * 8 + (oc >> 3)) * WP   \
                             + xx * 8 + (oc & 7)] = val;                        \
                    }                                                           \
                }                                                               \
            }                                                                   \
        }                                                                       \
    }

    C1_EPI(acc0, px0)
    C1_EPI(acc1, px0 + 16)
#undef C1_EPI
}

// =====================================================================
// K3: 9x9 local-max keep + candidate compaction (1 global atomic/block)
// =====================================================================
__global__ __launch_bounds__(256) void nms_kernel(const float* __restrict__ prob,
                                                  float* __restrict__ keep_out,
                                                  float* __restrict__ cand,
                                                  int* __restrict__ cnt)
{
    __shared__ float xs[40][40];
    __shared__ float rmax[40][32];
    __shared__ float clist[1024];
    __shared__ int csh;
    __shared__ int gbase;

    int bid = blockIdx.x;
    int tx = bid % 20;
    int ty = (bid / 20) % 15;
    int b = bid / 300;
    const float* pb = prob + (size_t)b * (HP * WP);
    int t = threadIdx.x;

    if (t == 0) csh = 0;

    for (int idx = t; idx < 1600; idx += 256) {
        int c = idx % 40, r = idx / 40;
        int gy = ty * 32 - 4 + r;
        int gx = tx * 32 - 4 + c;
        float v = -INFINITY;
        if (gy >= 0 && gy < HP && gx >= 0 && gx < WP) v = pb[gy * WP + gx];
        xs[r][c] = v;
    }
    __syncthreads();

    for (int idx = t; idx < 1280; idx += 256) {
        int c = idx & 31, r = idx >> 5;
        float m = xs[r][c];
#pragma unroll
        for (int d = 1; d < 9; ++d) m = fmaxf(m, xs[r][c + d]);
        rmax[r][c] = m;
    }
    __syncthreads();

    for (int idx = t; idx < 1024; idx += 256) {
        int c = idx & 31, ro = idx >> 5;
        float m = rmax[ro][c];
#pragma unroll
        for (int d = 1; d < 9; ++d) m = fmaxf(m, rmax[ro + d][c]);
        float v = xs[ro + 4][c + 4];
        float keep = (v == m) ? v : 0.f;
        keep_out[(size_t)b * (HP * WP) + (ty * 32 + ro) * WP + tx * 32 + c] = keep;
        if (keep > 0.f) {
            int i = atomicAdd(&csh, 1);
            clist[i] = keep;
        }
    }
    __syncthreads();

    int m = csh;
    if (m > 0) {
        if (t == 0) gbase = atomicAdd(&cnt[b * 32], m);
        __syncthreads();
        int gb = gbase;
        for (int i = t; i < m; i += 256) {
            int dst = gb + i;
            if (dst < CAND_MAX) cand[b * CAND_MAX + dst] = clist[i];
        }
    }
}

// =====================================================================
// K4: exact kth-largest (k=1000) per batch via 4-pass radix select
// =====================================================================
__global__ __launch_bounds__(256) void select_kernel(const float* __restrict__ cand,
                                                     const int* __restrict__ cnt,
                                                     float* __restrict__ kth)
{
    __shared__ unsigned hist[256];
    __shared__ unsigned sh_prefix, sh_K;

    int b = blockIdx.x;
    int t = threadIdx.x;
    int n = cnt[b * 32];
    if (n > CAND_MAX) n = CAND_MAX;
    if (n < TOPK) {
        if (t == 0) kth[b] = 0.f;
        return;
    }
    if (t == 0) { sh_prefix = 0u; sh_K = TOPK; }
    __syncthreads();
    const float* cb = cand + b * CAND_MAX;

    for (int pass = 3; pass >= 0; --pass) {
        hist[t] = 0u;
        __syncthreads();
        unsigned prefix = sh_prefix;
        unsigned himask = (pass == 3) ? 0u : (0xFFFFFFFFu << ((pass + 1) * 8));
        for (int i = t; i < n; i += 256) {
            unsigned u = __float_as_uint(cb[i]);
            if ((u & himask) == prefix)
                atomicAdd(&hist[(u >> (pass * 8)) & 255], 1u);
        }
        __syncthreads();
        if (t == 0) {
            unsigned K = sh_K, cum = 0;
            int sel = 0;
            for (int v2 = 255; v2 >= 0; --v2) {
                if (cum + hist[v2] >= K) { sel = v2; sh_K = K - cum; break; }
                cum += hist[v2];
            }
            sh_prefix = prefix | ((unsigned)sel << (pass * 8));
        }
        __syncthreads();
    }
    if (t == 0) kth[b] = __uint_as_float(sh_prefix);
}

// =====================================================================
// K5: threshold with kth + binarize
// =====================================================================
__global__ __launch_bounds__(256) void thresh_kernel(const float* __restrict__ keep,
                                                     const float* __restrict__ kth,
                                                     float* __restrict__ prob_nms,
                                                     float* __restrict__ pred)
{
    int i4 = blockIdx.x * 256 + threadIdx.x;
    int b = i4 / (HP * WP / 4);
    float tv = kth[b];
    float4 v = ((const float4*)keep)[i4];
    float4 o;
    o.x = (v.x >= tv) ? v.x : 0.f;
    o.y = (v.y >= tv) ? v.y : 0.f;
    o.z = (v.z >= tv) ? v.z : 0.f;
    o.w = (v.w >= tv) ? v.w : 0.f;
    ((float4*)prob_nms)[i4] = o;
    float4 pr;
    pr.x = (o.x >= DET_THRESH) ? 1.f : 0.f;
    pr.y = (o.y >= DET_THRESH) ? 1.f : 0.f;
    pr.z = (o.z >= DET_THRESH) ? 1.f : 0.f;
    pr.w = (o.w >= DET_THRESH) ? 1.f : 0.f;
    ((float4*)pred)[i4] = pr;
}

// =====================================================================
extern "C" void kernel_launch(void* const* d_in, const int* in_sizes, int n_in,
                              void* d_out, int out_size, void* d_ws, size_t ws_size,
                              hipStream_t stream) {
    const float* x   = (const float*)d_in[0];
    const float* wa  = (const float*)d_in[1];
    const float* ba  = (const float*)d_in[2];
    const float* ga  = (const float*)d_in[3];
    const float* bta = (const float*)d_in[4];
    const float* ma  = (const float*)d_in[5];
    const float* va  = (const float*)d_in[6];
    const float* wb  = (const float*)d_in[7];
    const float* bb  = (const float*)d_in[8];
    const float* gb  = (const float*)d_in[9];
    const float* btb = (const float*)d_in[10];
    const float* mb  = (const float*)d_in[11];
    const float* vb  = (const float*)d_in[12];

    float* out = (float*)d_out;
    float* ws  = (float*)d_ws;

    u16*   WB   = (u16*)ws;
    float* sa   = ws + SA_OFF;
    float* ta   = ws + TA_OFF;
    float* tbv  = ws + TB_OFF;
    u16*   WB1  = (u16*)(ws + WB1_OFF);
    float* h    = ws + H_OFF;
    float* cand = ws + CAND_OFF;
    int*   cnt  = (int*)(ws + CNT_OFF);
    float* kth  = ws + KTH_OFF;

    hipMemsetAsync((void*)cnt, 0, CNT_N * sizeof(int), stream);

    {
        int total = WT_N + 256 + COUT + WB1_U16N;
        prep_kernel<<<(total + 255) / 256, 256, 0, stream>>>(
            wa, ba, ga, bta, ma, va, wb, bb, gb, btb, mb, vb, WB, sa, ta, tbv, WB1);
    }

    conv3_kernel<<<2400, 256, 0, stream>>>(x, WB, sa, ta, h);

    conv1_kernel<<<(B_ * H_ * W_) / 128, 256, 0, stream>>>(
        h, WB1, tbv, out, out + PROB_OFF);

    nms_kernel<<<32 * 15 * 20, 256, 0, stream>>>(
        out + PROB_OFF, out + NMS_OFF, cand, cnt);

    select_kernel<<<B_, 256, 0, stream>>>(cand, cnt, kth);

    thresh_kernel<<<(PROB_N / 4) / 256, 256, 0, stream>>>(
        out + NMS_OFF, kth, out + NMS_OFF, out + PRED_OFF);
}